// Round 1
// baseline (134.503 us; speedup 1.0000x reference)
//
#include <hip/hip_runtime.h>

// Temporal IF-neuron spike quantizer, collapsed form:
//   mem = lam/2
//   for t: mem += x[t]; k = clamp(trunc(mem*128/lam), 0, 255);
//          out[t] = lam*k; mem -= lam*k
// (bit-plane decomposition == lam*k identity, verified absmax 0.0)
//
// Memory-bound streaming: 77 MB in + 77 MB out, zero reuse.
// This version: 2 vf4 slots per thread (i and i+stride), all 8 dwordx4
// loads issued before any compute -> 2x memory-level parallelism, two
// independent membrane dependency chains, half the workgroups.

#define T_STEPS 4

typedef float vf4 __attribute__((ext_vector_type(4)));

__device__ __forceinline__ vf4 step4(vf4& mem, const vf4 xv,
                                     const float lam, const float inv) {
    vf4 sp;
#pragma unroll
    for (int c = 0; c < 4; ++c) {
        float m = mem[c] + xv[c];
        int k = (int)(m * inv);                 // trunc toward zero == astype(int32)
        k = k < 0 ? 0 : (k > 255 ? 255 : k);    // compiler emits v_med3_i32
        float s = lam * (float)k;
        sp[c] = s;
        mem[c] = m - s;
    }
    return sp;
}

__global__ __launch_bounds__(256) void spike_scan_kernel(
    const vf4* __restrict__ x,
    const float* __restrict__ lam_p,
    vf4* __restrict__ out,
    int n4,        // vf4 count per timestep plane (S/4)
    int stride)    // second-slot offset = grid*block
{
    const int i0 = blockIdx.x * blockDim.x + threadIdx.x;
    const int i1 = i0 + stride;

    const float lam = lam_p[0];
    const float inv = 128.0f / lam;             // one divide, hoisted
    const float half_lam = 0.5f * lam;

    if (i1 < n4) {
        // Fast path (entire grid for the bench shape): 8 outstanding dwordx4.
        const vf4* pa = x + i0;
        const vf4* pb = x + i1;
        vf4 a0 = __builtin_nontemporal_load(pa);
        vf4 b0 = __builtin_nontemporal_load(pb);
        vf4 a1 = __builtin_nontemporal_load(pa + (size_t)n4);
        vf4 b1 = __builtin_nontemporal_load(pb + (size_t)n4);
        vf4 a2 = __builtin_nontemporal_load(pa + (size_t)2 * n4);
        vf4 b2 = __builtin_nontemporal_load(pb + (size_t)2 * n4);
        vf4 a3 = __builtin_nontemporal_load(pa + (size_t)3 * n4);
        vf4 b3 = __builtin_nontemporal_load(pb + (size_t)3 * n4);

        vf4 ma = {half_lam, half_lam, half_lam, half_lam};
        vf4 mb = ma;
        vf4 s;
        // Two independent membrane chains; stores retire as computed.
        s = step4(ma, a0, lam, inv); __builtin_nontemporal_store(s, out + i0);
        s = step4(mb, b0, lam, inv); __builtin_nontemporal_store(s, out + i1);
        s = step4(ma, a1, lam, inv); __builtin_nontemporal_store(s, out + (size_t)n4 + i0);
        s = step4(mb, b1, lam, inv); __builtin_nontemporal_store(s, out + (size_t)n4 + i1);
        s = step4(ma, a2, lam, inv); __builtin_nontemporal_store(s, out + (size_t)2 * n4 + i0);
        s = step4(mb, b2, lam, inv); __builtin_nontemporal_store(s, out + (size_t)2 * n4 + i1);
        s = step4(ma, a3, lam, inv); __builtin_nontemporal_store(s, out + (size_t)3 * n4 + i0);
        s = step4(mb, b3, lam, inv); __builtin_nontemporal_store(s, out + (size_t)3 * n4 + i1);
    } else if (i0 < n4) {
        // Tail (not taken at the bench shape; kept for generality).
        const vf4* pa = x + i0;
        vf4 a0 = __builtin_nontemporal_load(pa);
        vf4 a1 = __builtin_nontemporal_load(pa + (size_t)n4);
        vf4 a2 = __builtin_nontemporal_load(pa + (size_t)2 * n4);
        vf4 a3 = __builtin_nontemporal_load(pa + (size_t)3 * n4);

        vf4 ma = {half_lam, half_lam, half_lam, half_lam};
        vf4 s;
        s = step4(ma, a0, lam, inv); __builtin_nontemporal_store(s, out + i0);
        s = step4(ma, a1, lam, inv); __builtin_nontemporal_store(s, out + (size_t)n4 + i0);
        s = step4(ma, a2, lam, inv); __builtin_nontemporal_store(s, out + (size_t)2 * n4 + i0);
        s = step4(ma, a3, lam, inv); __builtin_nontemporal_store(s, out + (size_t)3 * n4 + i0);
    }
}

extern "C" void kernel_launch(void* const* d_in, const int* in_sizes, int n_in,
                              void* d_out, int out_size, void* d_ws, size_t ws_size,
                              hipStream_t stream) {
    const float* x = (const float*)d_in[0];
    const float* lam = (const float*)d_in[1];
    float* out = (float*)d_out;

    const int total = in_sizes[0];          // T*B*TOK*DIM
    const int spatial = total / T_STEPS;    // B*TOK*DIM
    const int n4 = spatial / 4;             // 1,204,224 at the bench shape

    const int block = 256;
    const int half = (n4 + 1) / 2;          // vf4 slots in the first half
    const int grid = (half + block - 1) / block;   // 2352 at the bench shape
    const int stride = grid * block;        // 602,112 — exact split, no tail

    spike_scan_kernel<<<grid, block, 0, stream>>>(
        (const vf4*)x, lam, (vf4*)out, n4, stride);
}